// Round 3
// baseline (3172.511 us; speedup 1.0000x reference)
//
#include <hip/hip_runtime.h>

// 2-layer bidirectional LSTM, B=256 T=2048 D=64, H1=16/dir, H2=8/dir.
// R3: LDS-free scan. One wave per (batch, direction) for BOTH layers.
//  - x-row for step s+1 loaded into registers at loop top (wave-uniform
//    address -> scalar loads), gx computed at loop bottom: HBM/L2 latency
//    and the 64 FMAs sit off the serial h-chain.
//  - h-matvec: lane j holds h_{j&(H-1)} redundantly; butterfly
//    sum_i shfl_xor(h,i) * W[j][k^i]. XOR is direction-symmetric (no DPP
//    rotation-direction ambiguity).
//  - gate exchange (i,f,g,o for unit k) via 3 parallel shfl_xor.
// No __shared__, no barriers, no vmcnt/lgkmcnt drains on the serial path.

constexpr int Bn = 256;
constexpr int Tn = 2048;

__device__ __forceinline__ float fast_rcp(float x) {
  return __builtin_amdgcn_rcpf(x);
}

// tanh(x) = 2*sigmoid(2x) - 1
__device__ __forceinline__ float tanh_fast(float x) {
  return fmaf(2.0f, fast_rcp(1.0f + __expf(-2.0f * x)), -1.0f);
}

// One direction of one layer. Din: input width, Hn: hidden per direction.
// Grid = 2*B (blockIdx = b*2 + dir), block = 64 = 1 wave.
// Gates j = lane & (4H-1); lanes beyond 4H replicate (l2: lanes 32-63).
// Output row layout: [fwd H | bwd H] (stride 2H), matching next layer input.
template <int Din, int Hn, int LOGH>
__global__ __launch_bounds__(64, 1) void scan_k(
    const float* __restrict__ xin,
    const float* __restrict__ wih_f, const float* __restrict__ whh_f,
    const float* __restrict__ bih_f, const float* __restrict__ bhh_f,
    const float* __restrict__ wih_b, const float* __restrict__ whh_b,
    const float* __restrict__ bih_b, const float* __restrict__ bhh_b,
    float* __restrict__ outp) {
  constexpr int NG = 4 * Hn;   // gates per direction
  constexpr int OW = 2 * Hn;   // output row width
  const int lane = threadIdx.x;
  const int j    = lane & (NG - 1);
  const int dir  = blockIdx.x & 1;
  const int b    = blockIdx.x >> 1;

  const float* wih = dir ? wih_b : wih_f;  // [NG][Din]
  const float* whh = dir ? whh_b : whh_f;  // [NG][Hn]
  const float* bih = dir ? bih_b : bih_f;
  const float* bhh = dir ? bhh_b : bhh_f;

  // Per-lane weight row in registers.
  float wihr[Din];
#pragma unroll
  for (int q = 0; q < Din / 4; ++q) {
    float4 v = reinterpret_cast<const float4*>(wih + j * Din)[q];
    wihr[4 * q + 0] = v.x; wihr[4 * q + 1] = v.y;
    wihr[4 * q + 2] = v.z; wihr[4 * q + 3] = v.w;
  }
  // Whh row permuted for the xor-butterfly: whhx[i] = Whh[j][k ^ i].
  const int k = j & (Hn - 1);
  float whhx[Hn];
#pragma unroll
  for (int i = 0; i < Hn; ++i) whhx[i] = whh[j * Hn + (k ^ i)];
  const float bias = bih[j] + bhh[j];

  const int grp = j >> LOGH;  // 0:i 1:f 2:g(tanh) 3:o
  const float gin  = (grp == 2) ? 2.0f : 1.0f;
  const float gout = (grp == 2) ? 2.0f : 1.0f;
  const float gsub = (grp == 2) ? -1.0f : 0.0f;

  const float* xb = xin + (size_t)b * Tn * Din;
  float*       ob = outp + (size_t)b * Tn * OW + dir * Hn;
  const int t0      = dir ? (Tn - 1) : 0;
  const int xstride = dir ? -Din : Din;
  const int ostride = dir ? -OW : OW;
  const float* xp = xb + (size_t)t0 * Din;
  float*       op = ob + (size_t)t0 * OW;

  // Register buffer holding one x row (wave-uniform values).
  float4 xn[Din / 4];
#pragma unroll
  for (int q = 0; q < Din / 4; ++q)
    xn[q] = reinterpret_cast<const float4*>(xp)[q];

  // gx = bias + x . Wih_row  (pure register FMAs, 4-way split chains)
  auto gxcalc = [&]() -> float {
    float a0 = bias, a1 = 0.f, a2 = 0.f, a3 = 0.f;
#pragma unroll
    for (int q = 0; q < Din / 4; ++q) {
      float4 v = xn[q];
      if ((q & 3) == 0) {
        a0 = fmaf(v.x, wihr[4 * q + 0], a0); a0 = fmaf(v.y, wihr[4 * q + 1], a0);
        a0 = fmaf(v.z, wihr[4 * q + 2], a0); a0 = fmaf(v.w, wihr[4 * q + 3], a0);
      } else if ((q & 3) == 1) {
        a1 = fmaf(v.x, wihr[4 * q + 0], a1); a1 = fmaf(v.y, wihr[4 * q + 1], a1);
        a1 = fmaf(v.z, wihr[4 * q + 2], a1); a1 = fmaf(v.w, wihr[4 * q + 3], a1);
      } else if ((q & 3) == 2) {
        a2 = fmaf(v.x, wihr[4 * q + 0], a2); a2 = fmaf(v.y, wihr[4 * q + 1], a2);
        a2 = fmaf(v.z, wihr[4 * q + 2], a2); a2 = fmaf(v.w, wihr[4 * q + 3], a2);
      } else {
        a3 = fmaf(v.x, wihr[4 * q + 0], a3); a3 = fmaf(v.y, wihr[4 * q + 1], a3);
        a3 = fmaf(v.z, wihr[4 * q + 2], a3); a3 = fmaf(v.w, wihr[4 * q + 3], a3);
      }
    }
    return (a0 + a1) + (a2 + a3);
  };

  float gx = gxcalc();   // gx for t0
  float h = 0.0f, c = 0.0f;

  for (int s = 0; s < Tn; ++s) {
    // Issue next-row loads now; consumed only at loop bottom (full step of slack).
    const float* xpn = (s + 1 < Tn) ? (xp + xstride) : xp;
#pragma unroll
    for (int q = 0; q < Din / 4; ++q)
      xn[q] = reinterpret_cast<const float4*>(xpn)[q];

    // ---- serial recurrence ----
    // h-matvec: lane j holds h_k (k = j & (H-1)); butterfly over xor offsets.
    float m0 = fmaf(h, whhx[0], gx), m1 = 0.0f;
#pragma unroll
    for (int i = 1; i < Hn; ++i) {
      float t = __shfl_xor(h, i, 64);
      if (i & 1) m1 = fmaf(t, whhx[i], m1);
      else       m0 = fmaf(t, whhx[i], m0);
    }
    const float g = m0 + m1;

    // activation: sigmoid, or tanh via 2*sigmoid(2x)-1 (one exp + one rcp)
    const float sg  = fast_rcp(1.0f + __expf(-gin * g));
    const float val = fmaf(gout, sg, gsub);

    // gate exchange: gates {i,f,g,o} of unit k live on lanes j ^ {0,H,2H,3H}
    const float v1 = __shfl_xor(val, Hn, 64);
    const float v2 = __shfl_xor(val, 2 * Hn, 64);
    const float v3 = __shfl_xor(val, 3 * Hn, 64);
    const float iv = (grp == 0) ? val : (grp == 1) ? v1 : (grp == 2) ? v2 : v3;
    const float fv = (grp == 1) ? val : (grp == 0) ? v1 : (grp == 3) ? v2 : v3;
    const float gv = (grp == 2) ? val : (grp == 3) ? v1 : (grp == 0) ? v2 : v3;
    const float ov = (grp == 3) ? val : (grp == 2) ? v1 : (grp == 1) ? v2 : v3;

    c = fmaf(fv, c, iv * gv);
    h = ov * tanh_fast(c);

    if (lane < Hn) op[lane] = h;

    // gx for next step (xn loaded above; latency fully covered by the chain)
    gx = gxcalc();
    xp = xpn;
    op += ostride;
  }
}

extern "C" void kernel_launch(void* const* d_in, const int* in_sizes, int n_in,
                              void* d_out, int out_size, void* d_ws, size_t ws_size,
                              hipStream_t stream) {
  const float* x     = (const float*)d_in[0];
  const float* wih1f = (const float*)d_in[1];
  const float* whh1f = (const float*)d_in[2];
  const float* bih1f = (const float*)d_in[3];
  const float* bhh1f = (const float*)d_in[4];
  const float* wih1b = (const float*)d_in[5];
  const float* whh1b = (const float*)d_in[6];
  const float* bih1b = (const float*)d_in[7];
  const float* bhh1b = (const float*)d_in[8];
  const float* wih2f = (const float*)d_in[9];
  const float* whh2f = (const float*)d_in[10];
  const float* bih2f = (const float*)d_in[11];
  const float* bhh2f = (const float*)d_in[12];
  const float* wih2b = (const float*)d_in[13];
  const float* whh2b = (const float*)d_in[14];
  const float* bih2b = (const float*)d_in[15];
  const float* bhh2b = (const float*)d_in[16];

  float* out1 = (float*)d_ws;   // [B][T][32] fp32 = 67.1 MB
  float* out  = (float*)d_out;  // [B][T][16] fp32

  scan_k<64, 16, 4><<<Bn * 2, 64, 0, stream>>>(
      x, wih1f, whh1f, bih1f, bhh1f, wih1b, whh1b, bih1b, bhh1b, out1);
  scan_k<32, 8, 3><<<Bn * 2, 64, 0, stream>>>(
      out1, wih2f, whh2f, bih2f, bhh2f, wih2b, whh2b, bih2b, bhh2b, out);
}

// Round 4
// 2042.051 us; speedup vs baseline: 1.5536x; 1.5536x over previous
//
#include <hip/hip_runtime.h>

// 2-layer bidirectional LSTM, B=256 T=2048 D=64, H1=16/dir, H2=8/dir.
// R4: register-resident scan (R1-R3 were scratch-spill-bound: VGPR_Count=56/64
// with 160+ floats of per-lane arrays -> arrays lived in scratch).
//  - ALL per-lane state in NAMED registers (macro-expanded w0..w15, n0..n15,
//    u0..u15): nothing for the allocator to demote to scratch.
//  - h-matvec: DPP row_ror butterfly (VALU pipe, ~2cy/op, zero LDS).
//    row_ror:r => lane l reads lane (l-r)&15 of its 16-row, which holds
//    h_{(k-r)&(H-1)}; weight u_r = Whh[j][(k-r)&(H-1)].
//  - x-row prefetch forced to VMEM (asm-opaque zero VGPR in the address) so
//    lgkmcnt is reserved for the 3 gate-exchange shuffles; vmcnt is waited
//    only at the gx dot, a full step after issue.
//  - gx joins at the END of the butterfly (off the critical path).

constexpr int Bn = 256;
constexpr int Tn = 2048;

#define REP16(X) X(0) X(1) X(2) X(3) X(4) X(5) X(6) X(7) \
                 X(8) X(9) X(10) X(11) X(12) X(13) X(14) X(15)
#define REP8(X)  X(0) X(1) X(2) X(3) X(4) X(5) X(6) X(7)

__device__ __forceinline__ float fast_rcp(float x) {
  return __builtin_amdgcn_rcpf(x);
}
__device__ __forceinline__ float tanh_fast(float x) {
  return fmaf(2.0f, fast_rcp(1.0f + __expf(-2.0f * x)), -1.0f);
}

// DPP rotate-right by R within each 16-lane row: dst[l] = src[(l-R)&15].
template <int R>
__device__ __forceinline__ float rotr16(float v) {
  static_assert(R >= 1 && R <= 15, "row_ror range");
  return __int_as_float(__builtin_amdgcn_mov_dpp(
      __float_as_int(v), 0x120 | R, 0xF, 0xF, true));
}

// 4 FMAs of float4 n##i * w##i into accumulator a.
#define FMA4(a, i)                                     \
  a = fmaf(n##i.x, w##i.x, a); a = fmaf(n##i.y, w##i.y, a); \
  a = fmaf(n##i.z, w##i.z, a); a = fmaf(n##i.w, w##i.w, a);

// ---------------- Layer 1: Din=64, H=16 ----------------
// grid = 2*B (blockIdx = b*2+dir), block = 64. lane = gate j; k=lane&15,
// grp=lane>>4 (0:i 1:f 2:g 3:o); each 16-lane DPP row is one gate group.
__global__ __launch_bounds__(64, 1) void l1_scan(
    const float* __restrict__ x,
    const float* __restrict__ wih_f, const float* __restrict__ whh_f,
    const float* __restrict__ bih_f, const float* __restrict__ bhh_f,
    const float* __restrict__ wih_b, const float* __restrict__ whh_b,
    const float* __restrict__ bih_b, const float* __restrict__ bhh_b,
    float* __restrict__ out1) {
  const int lane = threadIdx.x;
  const int dir  = blockIdx.x & 1;
  const int b    = blockIdx.x >> 1;

  const float* wih = dir ? wih_b : wih_f;  // [64][64]
  const float* whh = dir ? whh_b : whh_f;  // [64][16]
  const float bias = (dir ? bih_b : bih_f)[lane] + (dir ? bhh_b : bhh_f)[lane];

  const float4* wr = reinterpret_cast<const float4*>(wih + lane * 64);
#define DECLW(i) float4 w##i = wr[i];
  REP16(DECLW)
#undef DECLW

  const int k = lane & 15, grp = lane >> 4;
  const float* whr = whh + lane * 16;
#define DECLU(i) const float u##i = whr[(k - i) & 15];
  REP16(DECLU)
#undef DECLU

  const float gin  = (grp == 2) ? 2.0f : 1.0f;
  const float gout = (grp == 2) ? 2.0f : 1.0f;
  const float gsub = (grp == 2) ? -1.0f : 0.0f;

  // Opaque zero in a VGPR: makes x addresses "divergent" so loads stay VMEM.
  int zv;
  asm volatile("v_mov_b32 %0, 0" : "=v"(zv));

  const float* xb = x + (size_t)b * (Tn * 64);
  const float* xp = xb + (dir ? (size_t)(Tn - 1) * 64 : 0) + zv;
  float* op = out1 + (size_t)b * (Tn * 32) + dir * 16 +
              (dir ? (size_t)(Tn - 1) * 32 : 0);
  const int xstep = dir ? -64 : 64;
  const int ostep = dir ? -32 : 32;

#define DOT16(RES)                                                    \
  {                                                                   \
    float a0 = bias, a1 = 0.f, a2 = 0.f, a3 = 0.f;                    \
    FMA4(a0, 0)  FMA4(a1, 1)  FMA4(a2, 2)  FMA4(a3, 3)               \
    FMA4(a0, 4)  FMA4(a1, 5)  FMA4(a2, 6)  FMA4(a3, 7)               \
    FMA4(a0, 8)  FMA4(a1, 9)  FMA4(a2, 10) FMA4(a3, 11)              \
    FMA4(a0, 12) FMA4(a1, 13) FMA4(a2, 14) FMA4(a3, 15)              \
    RES = (a0 + a1) + (a2 + a3);                                      \
  }

  // Prologue: row t0 -> gx for step 0.
#define DECLN(i) float4 n##i = reinterpret_cast<const float4*>(xp)[i];
  REP16(DECLN)
#undef DECLN
  float gx;
  DOT16(gx)

  float h = 0.0f, c = 0.0f;

#pragma unroll 1
  for (int s = 0; s < Tn; ++s) {
    // Issue next-row loads (VMEM); consumed at loop bottom.
    const float* xpn = xp + ((s + 1 < Tn) ? xstep : 0);
#define LOADN(i) n##i = reinterpret_cast<const float4*>(xpn)[i];
    REP16(LOADN)
#undef LOADN

    // h-matvec butterfly: 15 DPP rotations, 4 accumulator chains.
    float m0 = h * u0, m1 = 0.f, m2 = 0.f, m3 = 0.f;
    m1 = fmaf(rotr16<1>(h),  u1,  m1);
    m2 = fmaf(rotr16<2>(h),  u2,  m2);
    m3 = fmaf(rotr16<3>(h),  u3,  m3);
    m0 = fmaf(rotr16<4>(h),  u4,  m0);
    m1 = fmaf(rotr16<5>(h),  u5,  m1);
    m2 = fmaf(rotr16<6>(h),  u6,  m2);
    m3 = fmaf(rotr16<7>(h),  u7,  m3);
    m0 = fmaf(rotr16<8>(h),  u8,  m0);
    m1 = fmaf(rotr16<9>(h),  u9,  m1);
    m2 = fmaf(rotr16<10>(h), u10, m2);
    m3 = fmaf(rotr16<11>(h), u11, m3);
    m0 = fmaf(rotr16<12>(h), u12, m0);
    m1 = fmaf(rotr16<13>(h), u13, m1);
    m2 = fmaf(rotr16<14>(h), u14, m2);
    m3 = fmaf(rotr16<15>(h), u15, m3);
    const float g = ((m0 + m1) + (m2 + m3)) + gx;  // gx joins at the END

    const float sg  = fast_rcp(1.0f + __expf(-gin * g));
    const float val = fmaf(gout, sg, gsub);

    // Gate exchange: {i,f,g,o} of unit k live on lanes j^{0,16,32,48}.
    const float e1 = __shfl_xor(val, 16, 64);
    const float e2 = __shfl_xor(val, 32, 64);
    const float e3 = __shfl_xor(val, 48, 64);
    const float iv = (grp == 0) ? val : (grp == 1) ? e1 : (grp == 2) ? e2 : e3;
    const float fv = (grp == 1) ? val : (grp == 0) ? e1 : (grp == 3) ? e2 : e3;
    const float gv = (grp == 2) ? val : (grp == 3) ? e1 : (grp == 0) ? e2 : e3;
    const float ov = (grp == 3) ? val : (grp == 2) ? e1 : (grp == 1) ? e2 : e3;

    c = fmaf(fv, c, iv * gv);
    h = ov * tanh_fast(c);

    DOT16(gx)  // gx for step s+1 (n* had a full chain of slack)

    if (lane < 16) op[lane] = h;
    op += ostep;
    xp = xpn;
  }
#undef DOT16
}

// ---------------- Layer 2: Din=32, H=8 ----------------
// grid = 2*B, block = 64; lanes 32-63 replicate lanes 0-31 (j = lane&31).
__global__ __launch_bounds__(64, 1) void l2_scan(
    const float* __restrict__ in,   // out1 [B][T][32]
    const float* __restrict__ wih_f, const float* __restrict__ whh_f,
    const float* __restrict__ bih_f, const float* __restrict__ bhh_f,
    const float* __restrict__ wih_b, const float* __restrict__ whh_b,
    const float* __restrict__ bih_b, const float* __restrict__ bhh_b,
    float* __restrict__ out) {      // [B][T][16]
  const int lane = threadIdx.x;
  const int j    = lane & 31;
  const int dir  = blockIdx.x & 1;
  const int b    = blockIdx.x >> 1;

  const float* wih = dir ? wih_b : wih_f;  // [32][32]
  const float* whh = dir ? whh_b : whh_f;  // [32][8]
  const float bias = (dir ? bih_b : bih_f)[j] + (dir ? bhh_b : bhh_f)[j];

  const float4* wr = reinterpret_cast<const float4*>(wih + j * 32);
#define DECLW(i) float4 w##i = wr[i];
  REP8(DECLW)
#undef DECLW

  const int k = j & 7, grp = j >> 3;
  const float* whr = whh + j * 8;
#define DECLU(i) const float u##i = whr[(k - i) & 7];
  REP8(DECLU)
#undef DECLU

  const float gin  = (grp == 2) ? 2.0f : 1.0f;
  const float gout = (grp == 2) ? 2.0f : 1.0f;
  const float gsub = (grp == 2) ? -1.0f : 0.0f;

  int zv;
  asm volatile("v_mov_b32 %0, 0" : "=v"(zv));

  const float* xb = in + (size_t)b * (Tn * 32);
  const float* xp = xb + (dir ? (size_t)(Tn - 1) * 32 : 0) + zv;
  float* op = out + (size_t)b * (Tn * 16) + dir * 8 +
              (dir ? (size_t)(Tn - 1) * 16 : 0);
  const int xstep = dir ? -32 : 32;
  const int ostep = dir ? -16 : 16;

#define DOT8(RES)                                                     \
  {                                                                   \
    float a0 = bias, a1 = 0.f, a2 = 0.f, a3 = 0.f;                    \
    FMA4(a0, 0) FMA4(a1, 1) FMA4(a2, 2) FMA4(a3, 3)                  \
    FMA4(a0, 4) FMA4(a1, 5) FMA4(a2, 6) FMA4(a3, 7)                  \
    RES = (a0 + a1) + (a2 + a3);                                      \
  }

#define DECLN(i) float4 n##i = reinterpret_cast<const float4*>(xp)[i];
  REP8(DECLN)
#undef DECLN
  float gx;
  DOT8(gx)

  float h = 0.0f, c = 0.0f;

#pragma unroll 1
  for (int s = 0; s < Tn; ++s) {
    const float* xpn = xp + ((s + 1 < Tn) ? xstep : 0);
#define LOADN(i) n##i = reinterpret_cast<const float4*>(xpn)[i];
    REP8(LOADN)
#undef LOADN

    // h-matvec: 7 DPP rotations (h pattern has period 8 within each 16-row,
    // so rotr16 delivers h_{(k-r)&7}).
    float m0 = h * u0, m1 = 0.f, m2 = 0.f, m3 = 0.f;
    m1 = fmaf(rotr16<1>(h), u1, m1);
    m2 = fmaf(rotr16<2>(h), u2, m2);
    m3 = fmaf(rotr16<3>(h), u3, m3);
    m0 = fmaf(rotr16<4>(h), u4, m0);
    m1 = fmaf(rotr16<5>(h), u5, m1);
    m2 = fmaf(rotr16<6>(h), u6, m2);
    m3 = fmaf(rotr16<7>(h), u7, m3);
    const float g = ((m0 + m1) + (m2 + m3)) + gx;

    const float sg  = fast_rcp(1.0f + __expf(-gin * g));
    const float val = fmaf(gout, sg, gsub);

    // Gate exchange within each 32-lane half: masks 8,16,24.
    const float e1 = __shfl_xor(val, 8, 64);
    const float e2 = __shfl_xor(val, 16, 64);
    const float e3 = __shfl_xor(val, 24, 64);
    const float iv = (grp == 0) ? val : (grp == 1) ? e1 : (grp == 2) ? e2 : e3;
    const float fv = (grp == 1) ? val : (grp == 0) ? e1 : (grp == 3) ? e2 : e3;
    const float gv = (grp == 2) ? val : (grp == 3) ? e1 : (grp == 0) ? e2 : e3;
    const float ov = (grp == 3) ? val : (grp == 2) ? e1 : (grp == 1) ? e2 : e3;

    c = fmaf(fv, c, iv * gv);
    h = ov * tanh_fast(c);

    DOT8(gx)

    if (lane < 8) op[lane] = h;
    op += ostep;
    xp = xpn;
  }
#undef DOT8
}

extern "C" void kernel_launch(void* const* d_in, const int* in_sizes, int n_in,
                              void* d_out, int out_size, void* d_ws, size_t ws_size,
                              hipStream_t stream) {
  const float* x     = (const float*)d_in[0];
  const float* wih1f = (const float*)d_in[1];
  const float* whh1f = (const float*)d_in[2];
  const float* bih1f = (const float*)d_in[3];
  const float* bhh1f = (const float*)d_in[4];
  const float* wih1b = (const float*)d_in[5];
  const float* whh1b = (const float*)d_in[6];
  const float* bih1b = (const float*)d_in[7];
  const float* bhh1b = (const float*)d_in[8];
  const float* wih2f = (const float*)d_in[9];
  const float* whh2f = (const float*)d_in[10];
  const float* bih2f = (const float*)d_in[11];
  const float* bhh2f = (const float*)d_in[12];
  const float* wih2b = (const float*)d_in[13];
  const float* whh2b = (const float*)d_in[14];
  const float* bih2b = (const float*)d_in[15];
  const float* bhh2b = (const float*)d_in[16];

  float* out1 = (float*)d_ws;   // [B][T][32] fp32 = 67.1 MB
  float* outp = (float*)d_out;  // [B][T][16] fp32

  l1_scan<<<Bn * 2, 64, 0, stream>>>(x, wih1f, whh1f, bih1f, bhh1f,
                                     wih1b, whh1b, bih1b, bhh1b, out1);
  l2_scan<<<Bn * 2, 64, 0, stream>>>(out1, wih2f, whh2f, bih2f, bhh2f,
                                     wih2b, whh2b, bih2b, bhh2b, outp);
}

// Round 7
// 1919.911 us; speedup vs baseline: 1.6524x; 1.0636x over previous
//
#include <hip/hip_runtime.h>

// 2-layer bidirectional LSTM, B=256 T=2048 D=64, H1=16/dir, H2=8/dir.
// R7: x staged through a 4-slot LDS ring via global_load_lds DMA (issued 3
// chunk-groups ahead), weights as plain loads (R4 kept them in registers:
// VGPR=80 = w64+u16). The giant asm-pinned register files of R5/R6 (which
// hard-crashed) are gone; asm surface = 1 store/step + 1 counted vmcnt +
// 1 DMA intrinsic per group.
//  - in-order vmcnt retirement (m135): wait N = #(VMEM ops issued after the
//    target DMA) = 2 DMAs + group stores -> l1 vmcnt(14), l2 vmcnt(26);
//    peeled groups 0..2 use 2/6/10 (l1) and 2/10/18 (l2). Compiler-added
//    VMEM ops only make the wait stricter (safe direction).
//  - h-store is asm global_store_dword (1 inst/step, deterministic count).
//  - serial path all-VALU: DPP row_ror butterfly + 3 shfl_xor gate exchange
//    (lane algebra identical to R4, which passed at absmax 9.8e-4).
//  - LDS reads are same-address broadcast across the wave: conflict-free.

constexpr int Bn = 256;
constexpr int Tn = 2048;

__device__ __forceinline__ float fast_rcp(float x) { return __builtin_amdgcn_rcpf(x); }
__device__ __forceinline__ float tanh_fast(float x) {
  return fmaf(2.0f, fast_rcp(1.0f + __expf(-2.0f * x)), -1.0f);
}

// DPP rotate-right by R within each 16-lane row: dst[l] = src[(l-R)&15].
template <int R>
__device__ __forceinline__ float rotr16(float v) {
  return __int_as_float(__builtin_amdgcn_mov_dpp(
      __float_as_int(v), 0x120 | R, 0xF, 0xF, true));
}

#define GST(addr, val) \
  asm volatile("global_store_dword %0, %1, off" :: "v"(addr), "v"(val) : "memory");

#define WAITV(N)                                              \
  do {                                                        \
    asm volatile("s_waitcnt vmcnt(" #N ")" ::: "memory");     \
    __builtin_amdgcn_sched_barrier(0);                        \
  } while (0)

// One DMA: 64 lanes x 16B = 1KB chunk. LDS dst = uniform base + lane*16.
#define DMA16(gsrc, ldst)                                         \
  __builtin_amdgcn_global_load_lds(                               \
      (const __attribute__((address_space(1))) float*)(gsrc),     \
      (__attribute__((address_space(3))) float*)(ldst), 16, 0, 0);

// 4 FMAs of LDS float4 xq_[I] * w##I into ACC.
#define FMAQ(ACC, I) { float4 v_ = xq_[I];                          \
    ACC = fmaf(v_.x, w##I.x, ACC); ACC = fmaf(v_.y, w##I.y, ACC);   \
    ACC = fmaf(v_.z, w##I.z, ACC); ACC = fmaf(v_.w, w##I.w, ACC); }

// ---------------- Layer 1: Din=64, H=16 ----------------
// grid = 2*B (blockIdx = b*2+dir), block = 64. lane = gate j; k=lane&15,
// grp=lane>>4 (0:i 1:f 2:g 3:o). Chunk = 4 rows x 64 floats = 1KB.
__global__ __launch_bounds__(64) void l1_scan(
    const float* __restrict__ x,
    const float* __restrict__ wih_f, const float* __restrict__ whh_f,
    const float* __restrict__ bih_f, const float* __restrict__ bhh_f,
    const float* __restrict__ wih_b, const float* __restrict__ whh_b,
    const float* __restrict__ bih_b, const float* __restrict__ bhh_b,
    float* __restrict__ out1) {
  constexpr int NC = Tn / 4;          // 512 chunks
  const int lane = threadIdx.x;
  const int dir  = blockIdx.x & 1;
  const int b    = blockIdx.x >> 1;

  __shared__ float xr[4 * 256];       // 4-slot ring, 4KB

  const float* xb = x + (size_t)b * (Tn * 64);

  // Prologue: DMA first 3 chunks into their slots (slot = chunk & 3).
  {
    const int m0 = dir ? NC - 1 : 0;
    const int md = dir ? -1 : 1;
#pragma unroll
    for (int p = 0; p < 3; ++p) {
      const int mc = m0 + p * md;
      DMA16(xb + (size_t)mc * 256 + lane * 4, xr + (mc & 3) * 256)
    }
  }

  const float* wih = dir ? wih_b : wih_f;  // [64][64]
  const float* whh = dir ? whh_b : whh_f;  // [64][16]
  const float bias = (dir ? bih_b : bih_f)[lane] + (dir ? bhh_b : bhh_f)[lane];

  const int k = lane & 15, grp = lane >> 4;
  const float gin  = (grp == 2) ? 2.0f : 1.0f;
  const float gout = (grp == 2) ? 2.0f : 1.0f;
  const float gsub = (grp == 2) ? -1.0f : 0.0f;

  // Weights: plain loads (R4 evidence: these stay register-resident).
  const float4* wr = reinterpret_cast<const float4*>(wih + lane * 64);
  float4 w0 = wr[0],  w1 = wr[1],  w2 = wr[2],  w3 = wr[3],
         w4 = wr[4],  w5 = wr[5],  w6 = wr[6],  w7 = wr[7],
         w8 = wr[8],  w9 = wr[9],  w10 = wr[10], w11 = wr[11],
         w12 = wr[12], w13 = wr[13], w14 = wr[14], w15 = wr[15];
  const float* whr = whh + lane * 16;
  const float u0 = whr[k], u1 = whr[(k - 1) & 15], u2 = whr[(k - 2) & 15],
              u3 = whr[(k - 3) & 15], u4 = whr[(k - 4) & 15],
              u5 = whr[(k - 5) & 15], u6 = whr[(k - 6) & 15],
              u7 = whr[(k - 7) & 15], u8 = whr[(k - 8) & 15],
              u9 = whr[(k - 9) & 15], u10 = whr[(k - 10) & 15],
              u11 = whr[(k - 11) & 15], u12 = whr[(k - 12) & 15],
              u13 = whr[(k - 13) & 15], u14 = whr[(k - 14) & 15],
              u15 = whr[(k - 15) & 15];

  const int ostep = dir ? -32 : 32;
  float* op = out1 + (size_t)b * (Tn * 32) + dir * 16 +
              (dir ? (size_t)(Tn - 1) * 32 : 0);

  float h = 0.0f, c = 0.0f;

#define STEP1(XROW) {                                                     \
    const float4* xq_ = reinterpret_cast<const float4*>(XROW);            \
    float a0 = bias, a1 = 0.f, a2 = 0.f, a3 = 0.f;                        \
    FMAQ(a0, 0)  FMAQ(a1, 1)  FMAQ(a2, 2)  FMAQ(a3, 3)                   \
    FMAQ(a0, 4)  FMAQ(a1, 5)  FMAQ(a2, 6)  FMAQ(a3, 7)                   \
    FMAQ(a0, 8)  FMAQ(a1, 9)  FMAQ(a2, 10) FMAQ(a3, 11)                  \
    FMAQ(a0, 12) FMAQ(a1, 13) FMAQ(a2, 14) FMAQ(a3, 15)                  \
    const float gx_ = (a0 + a1) + (a2 + a3);                              \
    float m0 = h * u0, m1 = 0.f, m2 = 0.f, m3 = 0.f;                      \
    m1 = fmaf(rotr16<1>(h),  u1,  m1);  m2 = fmaf(rotr16<2>(h),  u2,  m2); \
    m3 = fmaf(rotr16<3>(h),  u3,  m3);  m0 = fmaf(rotr16<4>(h),  u4,  m0); \
    m1 = fmaf(rotr16<5>(h),  u5,  m1);  m2 = fmaf(rotr16<6>(h),  u6,  m2); \
    m3 = fmaf(rotr16<7>(h),  u7,  m3);  m0 = fmaf(rotr16<8>(h),  u8,  m0); \
    m1 = fmaf(rotr16<9>(h),  u9,  m1);  m2 = fmaf(rotr16<10>(h), u10, m2); \
    m3 = fmaf(rotr16<11>(h), u11, m3);  m0 = fmaf(rotr16<12>(h), u12, m0); \
    m1 = fmaf(rotr16<13>(h), u13, m1);  m2 = fmaf(rotr16<14>(h), u14, m2); \
    m3 = fmaf(rotr16<15>(h), u15, m3);                                    \
    const float g_ = ((m0 + m1) + (m2 + m3)) + gx_;                       \
    const float sg_  = fast_rcp(1.0f + __expf(-gin * g_));                \
    const float val_ = fmaf(gout, sg_, gsub);                             \
    const float e1_ = __shfl_xor(val_, 16, 64);                           \
    const float e2_ = __shfl_xor(val_, 32, 64);                           \
    const float e3_ = __shfl_xor(val_, 48, 64);                           \
    const float iv_ = (grp == 0) ? val_ : (grp == 1) ? e1_ : (grp == 2) ? e2_ : e3_; \
    const float fv_ = (grp == 1) ? val_ : (grp == 0) ? e1_ : (grp == 3) ? e2_ : e3_; \
    const float gv_ = (grp == 2) ? val_ : (grp == 3) ? e1_ : (grp == 0) ? e2_ : e3_; \
    const float ov_ = (grp == 3) ? val_ : (grp == 2) ? e1_ : (grp == 1) ? e2_ : e3_; \
    c = fmaf(fv_, c, iv_ * gv_);                                          \
    h = ov_ * tanh_fast(c);                                               \
    if (lane < 16) { GST(op + lane, h) }                                  \
    op += ostep;                                                          \
  }

  // Group g consumes chunk mq (4 steps) and prefetches chunk mq±3.
#define GROUP1(NW, G) {                                                   \
    const int mq_ = dir ? (NC - 1 - (G)) : (G);                           \
    const float* sb_ = xr + (mq_ & 3) * 256;                              \
    WAITV(NW);                                                            \
    { const int mp_ = dir ? (mq_ - 3) : (mq_ + 3);                        \
      const int sl_ = mp_ & 3;                                            \
      const int mpc_ = mp_ < 0 ? 0 : (mp_ >= NC ? NC - 1 : mp_);          \
      DMA16(xb + (size_t)mpc_ * 256 + lane * 4, xr + sl_ * 256) }         \
    STEP1(sb_ + (dir ? 3 : 0) * 64)                                       \
    STEP1(sb_ + (dir ? 2 : 1) * 64)                                       \
    STEP1(sb_ + (dir ? 1 : 2) * 64)                                       \
    STEP1(sb_ + (dir ? 0 : 3) * 64)                                       \
  }

  GROUP1(2, 0)
  GROUP1(6, 1)
  GROUP1(10, 2)
#pragma unroll 1
  for (int g = 3; g < NC; ++g) {
    GROUP1(14, g)
  }
#undef GROUP1
#undef STEP1
}

// ---------------- Layer 2: Din=32, H=8 ----------------
// grid = 2*B, block = 64; lanes 32-63 replicate lanes 0-31 (j = lane&31).
// Chunk = 8 rows x 32 floats = 1KB.
__global__ __launch_bounds__(64) void l2_scan(
    const float* __restrict__ in,   // out1 [B][T][32]
    const float* __restrict__ wih_f, const float* __restrict__ whh_f,
    const float* __restrict__ bih_f, const float* __restrict__ bhh_f,
    const float* __restrict__ wih_b, const float* __restrict__ whh_b,
    const float* __restrict__ bih_b, const float* __restrict__ bhh_b,
    float* __restrict__ out) {      // [B][T][16]
  constexpr int NC = Tn / 8;          // 256 chunks
  const int lane = threadIdx.x;
  const int j    = lane & 31;
  const int dir  = blockIdx.x & 1;
  const int b    = blockIdx.x >> 1;

  __shared__ float xr[4 * 256];       // 4-slot ring, 4KB

  const float* ib = in + (size_t)b * (Tn * 32);

  {
    const int m0 = dir ? NC - 1 : 0;
    const int md = dir ? -1 : 1;
#pragma unroll
    for (int p = 0; p < 3; ++p) {
      const int mc = m0 + p * md;
      DMA16(ib + (size_t)mc * 256 + lane * 4, xr + (mc & 3) * 256)
    }
  }

  const float* wih = dir ? wih_b : wih_f;  // [32][32]
  const float* whh = dir ? whh_b : whh_f;  // [32][8]
  const float bias = (dir ? bih_b : bih_f)[j] + (dir ? bhh_b : bhh_f)[j];

  const int k = j & 7, grp = j >> 3;
  const float gin  = (grp == 2) ? 2.0f : 1.0f;
  const float gout = (grp == 2) ? 2.0f : 1.0f;
  const float gsub = (grp == 2) ? -1.0f : 0.0f;

  const float4* wr = reinterpret_cast<const float4*>(wih + j * 32);
  float4 w0 = wr[0], w1 = wr[1], w2 = wr[2], w3 = wr[3],
         w4 = wr[4], w5 = wr[5], w6 = wr[6], w7 = wr[7];
  const float* whr = whh + j * 8;
  const float u0 = whr[k], u1 = whr[(k - 1) & 7], u2 = whr[(k - 2) & 7],
              u3 = whr[(k - 3) & 7], u4 = whr[(k - 4) & 7],
              u5 = whr[(k - 5) & 7], u6 = whr[(k - 6) & 7],
              u7 = whr[(k - 7) & 7];

  const int ostep = dir ? -16 : 16;
  float* op = out + (size_t)b * (Tn * 16) + dir * 8 +
              (dir ? (size_t)(Tn - 1) * 16 : 0);

  float h = 0.0f, c = 0.0f;

#define STEP2(XROW) {                                                     \
    const float4* xq_ = reinterpret_cast<const float4*>(XROW);            \
    float a0 = bias, a1 = 0.f, a2 = 0.f, a3 = 0.f;                        \
    FMAQ(a0, 0) FMAQ(a1, 1) FMAQ(a2, 2) FMAQ(a3, 3)                      \
    FMAQ(a0, 4) FMAQ(a1, 5) FMAQ(a2, 6) FMAQ(a3, 7)                      \
    const float gx_ = (a0 + a1) + (a2 + a3);                              \
    float m0 = h * u0, m1 = 0.f, m2 = 0.f, m3 = 0.f;                      \
    m1 = fmaf(rotr16<1>(h), u1, m1);  m2 = fmaf(rotr16<2>(h), u2, m2);    \
    m3 = fmaf(rotr16<3>(h), u3, m3);  m0 = fmaf(rotr16<4>(h), u4, m0);    \
    m1 = fmaf(rotr16<5>(h), u5, m1);  m2 = fmaf(rotr16<6>(h), u6, m2);    \
    m3 = fmaf(rotr16<7>(h), u7, m3);                                      \
    const float g_ = ((m0 + m1) + (m2 + m3)) + gx_;                       \
    const float sg_  = fast_rcp(1.0f + __expf(-gin * g_));                \
    const float val_ = fmaf(gout, sg_, gsub);                             \
    const float e1_ = __shfl_xor(val_, 8, 64);                            \
    const float e2_ = __shfl_xor(val_, 16, 64);                           \
    const float e3_ = __shfl_xor(val_, 24, 64);                           \
    const float iv_ = (grp == 0) ? val_ : (grp == 1) ? e1_ : (grp == 2) ? e2_ : e3_; \
    const float fv_ = (grp == 1) ? val_ : (grp == 0) ? e1_ : (grp == 3) ? e2_ : e3_; \
    const float gv_ = (grp == 2) ? val_ : (grp == 3) ? e1_ : (grp == 0) ? e2_ : e3_; \
    const float ov_ = (grp == 3) ? val_ : (grp == 2) ? e1_ : (grp == 1) ? e2_ : e3_; \
    c = fmaf(fv_, c, iv_ * gv_);                                          \
    h = ov_ * tanh_fast(c);                                               \
    if (lane < 8) { GST(op + lane, h) }                                   \
    op += ostep;                                                          \
  }

#define GROUP2(NW, G) {                                                   \
    const int mq_ = dir ? (NC - 1 - (G)) : (G);                           \
    const float* sb_ = xr + (mq_ & 3) * 256;                              \
    WAITV(NW);                                                            \
    { const int mp_ = dir ? (mq_ - 3) : (mq_ + 3);                        \
      const int sl_ = mp_ & 3;                                            \
      const int mpc_ = mp_ < 0 ? 0 : (mp_ >= NC ? NC - 1 : mp_);          \
      DMA16(ib + (size_t)mpc_ * 256 + lane * 4, xr + sl_ * 256) }         \
    STEP2(sb_ + (dir ? 7 : 0) * 32)                                       \
    STEP2(sb_ + (dir ? 6 : 1) * 32)                                       \
    STEP2(sb_ + (dir ? 5 : 2) * 32)                                       \
    STEP2(sb_ + (dir ? 4 : 3) * 32)                                       \
    STEP2(sb_ + (dir ? 3 : 4) * 32)                                       \
    STEP2(sb_ + (dir ? 2 : 5) * 32)                                       \
    STEP2(sb_ + (dir ? 1 : 6) * 32)                                       \
    STEP2(sb_ + (dir ? 0 : 7) * 32)                                       \
  }

  GROUP2(2, 0)
  GROUP2(10, 1)
  GROUP2(18, 2)
#pragma unroll 1
  for (int g = 3; g < NC; ++g) {
    GROUP2(26, g)
  }
#undef GROUP2
#undef STEP2
}

extern "C" void kernel_launch(void* const* d_in, const int* in_sizes, int n_in,
                              void* d_out, int out_size, void* d_ws, size_t ws_size,
                              hipStream_t stream) {
  const float* x     = (const float*)d_in[0];
  const float* wih1f = (const float*)d_in[1];
  const float* whh1f = (const float*)d_in[2];
  const float* bih1f = (const float*)d_in[3];
  const float* bhh1f = (const float*)d_in[4];
  const float* wih1b = (const float*)d_in[5];
  const float* whh1b = (const float*)d_in[6];
  const float* bih1b = (const float*)d_in[7];
  const float* bhh1b = (const float*)d_in[8];
  const float* wih2f = (const float*)d_in[9];
  const float* whh2f = (const float*)d_in[10];
  const float* bih2f = (const float*)d_in[11];
  const float* bhh2f = (const float*)d_in[12];
  const float* wih2b = (const float*)d_in[13];
  const float* whh2b = (const float*)d_in[14];
  const float* bih2b = (const float*)d_in[15];
  const float* bhh2b = (const float*)d_in[16];

  float* out1 = (float*)d_ws;   // [B][T][32] fp32 = 67.1 MB
  float* outp = (float*)d_out;  // [B][T][16] fp32

  l1_scan<<<Bn * 2, 64, 0, stream>>>(x, wih1f, whh1f, bih1f, bhh1f,
                                     wih1b, whh1b, bih1b, bhh1b, out1);
  l2_scan<<<Bn * 2, 64, 0, stream>>>(out1, wih2f, whh2f, bih2f, bhh2f,
                                     wih2b, whh2b, bih2b, bhh2b, outp);
}